// Round 7
// baseline (138.789 us; speedup 1.0000x reference)
//
#include <hip/hip_runtime.h>
#include <stdint.h>

typedef unsigned short ushort_t;
typedef __attribute__((ext_vector_type(8))) short short8v;   // 8 x bf16
typedef __attribute__((ext_vector_type(4))) float f32x4;     // MFMA acc

// ws: At bf16 [16][128][512] (2 MiB) | Wt bf16 [16][512][512] (8 MiB)
#define AT_ELEMS (16u * 128u * 512u)
#define WT_ELEMS (16u * 512u * 512u)
#define WS_NEEDED ((size_t)(AT_ELEMS + WT_ELEMS) * 2u)

__host__ __device__ constexpr int ga_sign_i(int a, int b) {
  int t = a >> 1, sw = 0;
  while (t) {
    int x = t & b;
    while (x) { sw += x & 1; x >>= 1; }
    t >>= 1;
  }
  return (sw & 1) ? -1 : 1;
}

struct SignTab { int s[16][16]; };
constexpr SignTab make_tab() {
  SignTab t{};
  for (int i = 0; i < 16; i++)
    for (int j = 0; j < 16; j++) t.s[i][j] = ga_sign_i(i, j);
  return t;
}
constexpr SignTab STAB = make_tab();

__device__ __forceinline__ ushort_t f2bf(float f) {
  unsigned u = __float_as_uint(f);
  u = (u + 0x7FFFu + ((u >> 16) & 1u)) >> 16;   // RNE
  return (ushort_t)u;
}

__device__ __forceinline__ short8v neg_bf16x8(short8v v) {
  const short m = (short)0x8000;
  return v ^ (short8v){m, m, m, m, m, m, m, m};
}

// ---------------------------------------------------------------------------
// prep v2 (unchanged from R5/R6): LDS-transpose, one block per source row.
// ---------------------------------------------------------------------------
#define PREP_BLOCKS (128 + 512)

__global__ __launch_bounds__(256) void prep_kernel(const float* __restrict__ x,
                                                   const float* __restrict__ w,
                                                   ushort_t* __restrict__ At,
                                                   ushort_t* __restrict__ Wt) {
  __shared__ __align__(16) ushort_t Ls[16 * 512];   // 16 KB: Ls[i][n]

  const int r = blockIdx.x;
  const int t = threadIdx.x;
  const bool isx = (r < 128);
  const float* src = isx ? (x + (size_t)r * 8192) : (w + (size_t)(r - 128) * 8192);
  ushort_t* dst    = isx ? (At + (size_t)r * 512)  : (Wt + (size_t)(r - 128) * 512);
  const int dplane = isx ? (128 * 512) : (512 * 512);

#pragma unroll
  for (int k = 0; k < 4; k++) {
    const int uu = t + k * 256;
    const float4* sp = (const float4*)(src + (size_t)uu * 8);
    const float4 v0 = sp[0], v1 = sp[1];
    const int n = uu >> 1, i0 = (uu & 1) * 8;
    ushort_t* lp = &Ls[i0 * 512 + n];
    lp[0]    = f2bf(v0.x); lp[512]  = f2bf(v0.y);
    lp[1024] = f2bf(v0.z); lp[1536] = f2bf(v0.w);
    lp[2048] = f2bf(v1.x); lp[2560] = f2bf(v1.y);
    lp[3072] = f2bf(v1.z); lp[3584] = f2bf(v1.w);
  }
  __syncthreads();

  const int j = t >> 4, c = t & 15;
#pragma unroll
  for (int g = 0; g < 4; g++) {
    const int chunk = c + g * 16;                       // n8 index 0..63
    const short8v vv = *(const short8v*)&Ls[j * 512 + chunk * 8];
    *(short8v*)(dst + (size_t)j * dplane + chunk * 8) = vv;
  }
}

// ---------------------------------------------------------------------------
// gemm v7 = DIAGNOSTIC PROBE on the proven R6 structure (deliberate temporary
// regression). The working gemm has NEVER appeared in the top-5 counter table
// (masked by the harness's 43-46us workspace-poison fills), so its true time
// and counters are unknown; three theories about it have been falsified by
// neutral results. This probe runs the K-loop 4 PASSES, keeping only the last
// pass's acc (passes 0-2 held live via asm-volatile keep-alives on every acc
// element, rule #17 -> no DCE), so the OUTPUT IS BIT-IDENTICAL to R6.
//   -> Delta(dur) = 3 x gemm_true  (splits the ~50us kernel-side window)
//   -> gemm dispatch becomes top-5-visible with full counters (MfmaUtil,
//      FETCH_SIZE, bank conflicts, occupancy) in both outcome branches.
// Structure per pass: byte-identical to R6 (staging maps, swizzle, T1 remap,
// i-outer inner loop, __syncthreads schedule, epilogue).
// ---------------------------------------------------------------------------
__global__ __launch_bounds__(256, 1) void gemm_kernel(const ushort_t* __restrict__ At,
                                                      const ushort_t* __restrict__ Wt,
                                                      const float* __restrict__ bias,
                                                      float* __restrict__ out) {
  __shared__ __align__(16) ushort_t smem[65536];   // 128 KB

  const int bid = blockIdx.x;          // 0..255
  const int xcd = bid & 7;             // T1 remap (neutral, kept from R6)
  const int local = bid >> 3;
  const int ut = xcd * 4 + (local & 3);
  const int bt = local >> 2;
  const int u0 = ut * 16, b0 = bt * 16;

  const int tid = threadIdx.x;
  const int wv = tid >> 6, lane = tid & 63;
  const int la = lane & 15, q = lane >> 4;

  // --- staging (DMA) addressing ---
  const int srow = tid >> 4;
  const int sps = tid & 15;
  const int sp = sps ^ (srow & 7);
  const int sc = sp >> 2, sq = sp & 3;

  const ushort_t* AxB = At + (size_t)(b0 + srow) * 512 + sc * 32 + sq * 8;
  const ushort_t* WxB = Wt + (size_t)(u0 + srow) * 512 + sc * 32 + sq * 8;

  // --- frag read addressing ---
  const int pr = wv * 4 + q;
  const int lbx = la * 256 + ((pr ^ (la & 7)) * 16);

  f32x4 acc[16];
  const char* sm = (const char*)smem;

#pragma unroll 1
  for (int pass = 0; pass < 4; ++pass) {
#pragma unroll
    for (int k = 0; k < 16; k++) acc[k] = (f32x4){0.f, 0.f, 0.f, 0.f};

#pragma unroll 1
    for (int kt = 0; kt < 4; kt++) {
#pragma unroll
      for (int i = 0; i < 16; i++)
        __builtin_amdgcn_global_load_lds(
            (const __attribute__((address_space(1))) unsigned int*)(AxB + (size_t)i * 65536 + kt * 128),
            (__attribute__((address_space(3))) unsigned int*)(&smem[(i * 256 + wv * 64) * 8]),
            16, 0, 0);
#pragma unroll
      for (int i = 0; i < 16; i++)
        __builtin_amdgcn_global_load_lds(
            (const __attribute__((address_space(1))) unsigned int*)(WxB + (size_t)i * 262144 + kt * 128),
            (__attribute__((address_space(3))) unsigned int*)(&smem[32768 + (i * 256 + wv * 64) * 8]),
            16, 0, 0);
      __syncthreads();

      short8v bv[16];
#pragma unroll
      for (int j = 0; j < 16; j++)
        bv[j] = *(const short8v*)(sm + 65536 + j * 4096 + lbx);

#pragma unroll
      for (int i = 0; i < 16; i++) {
        const short8v a = *(const short8v*)(sm + i * 4096 + lbx);
        const short8v na = neg_bf16x8(a);
#pragma unroll
        for (int j = 0; j < 16; j++) {
          const int k = i ^ j;                 // compile-time after unroll
          acc[k] = __builtin_amdgcn_mfma_f32_16x16x32_bf16(
              (STAB.s[i][j] < 0) ? na : a, bv[j], acc[k], 0, 0, 0);
        }
      }
      __syncthreads();
    }

    // keep-alive: prevent DCE of passes 0-2 (rule #17); last pass feeds epilogue.
    if (pass < 3) {
#pragma unroll
      for (int k = 0; k < 16; k++)
        asm volatile("" :: "v"(acc[k][0]), "v"(acc[k][1]), "v"(acc[k][2]), "v"(acc[k][3]));
    }
  }

  // --- epilogue (unchanged): cross-wave reduction + bias + float4 out ---
  float* red = (float*)smem;
#pragma unroll
  for (int g = 0; g < 4; g++) {
#pragma unroll
    for (int r2 = 0; r2 < 4; r2++) {
      float4 v = make_float4(acc[g * 4 + 0][r2], acc[g * 4 + 1][r2],
                             acc[g * 4 + 2][r2], acc[g * 4 + 3][r2]);
      int row = q * 4 + r2;                  // C/D: row = quad*4 + reg (m89)
      *(float4*)&red[(((wv * 16 + row) * 16 + la) << 4) + g * 4] = v;
    }
  }
  __syncthreads();

  const int row = tid >> 4, col = tid & 15;
  float4 o[4];
#pragma unroll
  for (int g = 0; g < 4; g++)
    o[g] = *(const float4*)&bias[(u0 + col) * 16 + g * 4];
#pragma unroll
  for (int w2 = 0; w2 < 4; w2++) {
#pragma unroll
    for (int g = 0; g < 4; g++) {
      float4 v = *(const float4*)&red[(((w2 * 16 + row) * 16 + col) << 4) + g * 4];
      o[g].x += v.x; o[g].y += v.y; o[g].z += v.z; o[g].w += v.w;
    }
  }
#pragma unroll
  for (int g = 0; g < 4; g++)
    *(float4*)&out[((size_t)(b0 + row) * 512 + (u0 + col)) * 16 + g * 4] = o[g];
}

// ---------------------------------------------------------------------------
// fallback (ws too small): exact fp32, slow but correct
// ---------------------------------------------------------------------------
__global__ __launch_bounds__(256) void naive_kernel(const float* __restrict__ x,
                                                    const float* __restrict__ w,
                                                    const float* __restrict__ bias,
                                                    float* __restrict__ out) {
  int t = blockIdx.x * 256 + threadIdx.x;
  if (t >= 128 * 512 * 16) return;
  int k = t & 15;
  int u = (t >> 4) & 511;
  int b = t >> 13;
  float sgn[16];
#pragma unroll
  for (int i = 0; i < 16; i++) sgn[i] = (float)ga_sign_i(i, i ^ k);
  float acc = bias[u * 16 + k];
  for (int n = 0; n < 512; n++) {
    const float* xp = x + ((size_t)(b * 512 + n)) * 16;
    const float* wp = w + ((size_t)(u * 512 + n)) * 16;
#pragma unroll
    for (int i = 0; i < 16; i++)
      acc += xp[i] * sgn[i] * wp[i ^ k];
  }
  out[t] = acc;
}

extern "C" void kernel_launch(void* const* d_in, const int* in_sizes, int n_in,
                              void* d_out, int out_size, void* d_ws, size_t ws_size,
                              hipStream_t stream) {
  const float* x    = (const float*)d_in[0];
  const float* w    = (const float*)d_in[1];
  const float* bias = (const float*)d_in[2];
  float* out = (float*)d_out;

  if (ws_size >= WS_NEEDED && d_ws != nullptr) {
    ushort_t* At = (ushort_t*)d_ws;
    ushort_t* Wt = At + AT_ELEMS;

    prep_kernel<<<PREP_BLOCKS, 256, 0, stream>>>(x, w, At, Wt);
    gemm_kernel<<<256, 256, 0, stream>>>(At, Wt, bias, out);
  } else {
    naive_kernel<<<(128 * 512 * 16) / 256, 256, 0, stream>>>(x, w, bias, out);
  }
}

// Round 8
// 100.629 us; speedup vs baseline: 1.3792x; 1.3792x over previous
//
#include <hip/hip_runtime.h>
#include <stdint.h>

typedef unsigned short ushort_t;
typedef __attribute__((ext_vector_type(8))) short short8v;   // 8 x bf16
typedef __attribute__((ext_vector_type(4))) float f32x4;     // MFMA acc

// ws: At bf16 [16][128][512] (2 MiB) | Wt bf16 [16][512][512] (8 MiB)
#define AT_ELEMS (16u * 128u * 512u)
#define WT_ELEMS (16u * 512u * 512u)
#define WS_NEEDED ((size_t)(AT_ELEMS + WT_ELEMS) * 2u)

__host__ __device__ constexpr int ga_sign_i(int a, int b) {
  int t = a >> 1, sw = 0;
  while (t) {
    int x = t & b;
    while (x) { sw += x & 1; x >>= 1; }
    t >>= 1;
  }
  return (sw & 1) ? -1 : 1;
}

struct SignTab { int s[16][16]; };
constexpr SignTab make_tab() {
  SignTab t{};
  for (int i = 0; i < 16; i++)
    for (int j = 0; j < 16; j++) t.s[i][j] = ga_sign_i(i, j);
  return t;
}
constexpr SignTab STAB = make_tab();

__device__ __forceinline__ ushort_t f2bf(float f) {
  unsigned u = __float_as_uint(f);
  u = (u + 0x7FFFu + ((u >> 16) & 1u)) >> 16;   // RNE
  return (ushort_t)u;
}

__device__ __forceinline__ short8v neg_bf16x8(short8v v) {
  const short m = (short)0x8000;
  return v ^ (short8v){m, m, m, m, m, m, m, m};
}

// ---------------------------------------------------------------------------
// prep v2 (unchanged, proven-neutral-or-better): LDS-transpose, one block per
// source row; vectorized loads, short8 stores. Layouts bit-identical.
// ---------------------------------------------------------------------------
#define PREP_BLOCKS (128 + 512)

__global__ __launch_bounds__(256) void prep_kernel(const float* __restrict__ x,
                                                   const float* __restrict__ w,
                                                   ushort_t* __restrict__ At,
                                                   ushort_t* __restrict__ Wt) {
  __shared__ __align__(16) ushort_t Ls[16 * 512];   // 16 KB: Ls[i][n]

  const int r = blockIdx.x;
  const int t = threadIdx.x;
  const bool isx = (r < 128);
  const float* src = isx ? (x + (size_t)r * 8192) : (w + (size_t)(r - 128) * 8192);
  ushort_t* dst    = isx ? (At + (size_t)r * 512)  : (Wt + (size_t)(r - 128) * 512);
  const int dplane = isx ? (128 * 512) : (512 * 512);

#pragma unroll
  for (int k = 0; k < 4; k++) {
    const int uu = t + k * 256;
    const float4* sp = (const float4*)(src + (size_t)uu * 8);
    const float4 v0 = sp[0], v1 = sp[1];
    const int n = uu >> 1, i0 = (uu & 1) * 8;
    ushort_t* lp = &Ls[i0 * 512 + n];
    lp[0]    = f2bf(v0.x); lp[512]  = f2bf(v0.y);
    lp[1024] = f2bf(v0.z); lp[1536] = f2bf(v0.w);
    lp[2048] = f2bf(v1.x); lp[2560] = f2bf(v1.y);
    lp[3072] = f2bf(v1.z); lp[3584] = f2bf(v1.w);
  }
  __syncthreads();

  const int j = t >> 4, c = t & 15;
#pragma unroll
  for (int g = 0; g < 4; g++) {
    const int chunk = c + g * 16;                       // n8 index 0..63
    const short8v vv = *(const short8v*)&Ls[j * 512 + chunk * 8];
    *(short8v*)(dst + (size_t)j * dplane + chunk * 8) = vv;
  }
}

// ---------------------------------------------------------------------------
// warm_kernel (NEW, R7-evidence-driven): L2 prefetch between prep and gemm.
// R7 probe measured gemm = 42.4us COLD vs 14.7us WARM (4-pass probe,
// cross-checked against the R6 window to 0.1us): ~2/3 of gemm is first-touch
// of freshly-written At/Wt, pulled cross-XCD through 4 drain-locked stages
// (vmcnt(0)+barrier, 1 block/CU, zero latency tolerance) at ~0.4 TB/s
// effective. This kernel moves the SAME 12 MB through the same fabric path
// but as pure streaming (no barriers, no drains, full concurrency, perfectly
// coalesced dwordx4 over contiguous 16 KB plane-slices), with the SAME
// bid->(ut,bt)->XCD map as gemm so each block fills the L2 its successor
// gemm block will read. Loads kept live via asm (rule #17). Worst case
// (no L2 persistence across dispatch): converts dirty-peer-L2 misses into
// clean L3 hits - still positive.
// ---------------------------------------------------------------------------
__global__ __launch_bounds__(256) void warm_kernel(const ushort_t* __restrict__ At,
                                                   const ushort_t* __restrict__ Wt) {
  const int bid = blockIdx.x;          // 0..255, same dispatch pattern as gemm
  const int xcd = bid & 7;
  const int local = bid >> 3;
  const int ut = xcd * 4 + (local & 3);
  const int bt = local >> 2;
  const int b0 = bt * 16, u0 = ut * 16;
  const int t = threadIdx.x;

  unsigned ax = 0, ay = 0, az = 0, aw = 0;
#pragma unroll
  for (int i = 0; i < 16; i++) {
    // Each plane-slice is a contiguous 16 KB run (rows b0..b0+16 / u0..u0+16).
    const uint4* pa = (const uint4*)(At + (size_t)(i * 128 + b0) * 512) + t;
    const uint4* pw = (const uint4*)(Wt + (size_t)(i * 512 + u0) * 512) + t;
#pragma unroll
    for (int k = 0; k < 4; k++) {
      const uint4 a = pa[k * 256];
      const uint4 w = pw[k * 256];
      ax ^= a.x ^ w.x; ay ^= a.y ^ w.y; az ^= a.z ^ w.z; aw ^= a.w ^ w.w;
    }
  }
  asm volatile("" :: "v"(ax), "v"(ay), "v"(az), "v"(aw));   // keep loads live
}

// ---------------------------------------------------------------------------
// gemm (BYTE-IDENTICAL to R6's 94.6us kernel): R0 staging map + swizzle,
// T1 XCD remap (neutral alone, but aligned with warm_kernel's map),
// single-buffer 4-stage schedule, i-outer inner loop, proven epilogue.
// ---------------------------------------------------------------------------
__global__ __launch_bounds__(256, 1) void gemm_kernel(const ushort_t* __restrict__ At,
                                                      const ushort_t* __restrict__ Wt,
                                                      const float* __restrict__ bias,
                                                      float* __restrict__ out) {
  __shared__ __align__(16) ushort_t smem[65536];   // 128 KB

  const int bid = blockIdx.x;          // 0..255
  const int xcd = bid & 7;
  const int local = bid >> 3;
  const int ut = xcd * 4 + (local & 3);
  const int bt = local >> 2;
  const int u0 = ut * 16, b0 = bt * 16;

  const int tid = threadIdx.x;
  const int wv = tid >> 6, lane = tid & 63;
  const int la = lane & 15, q = lane >> 4;

  // --- staging (DMA) addressing ---
  const int srow = tid >> 4;
  const int sps = tid & 15;
  const int sp = sps ^ (srow & 7);
  const int sc = sp >> 2, sq = sp & 3;

  const ushort_t* AxB = At + (size_t)(b0 + srow) * 512 + sc * 32 + sq * 8;
  const ushort_t* WxB = Wt + (size_t)(u0 + srow) * 512 + sc * 32 + sq * 8;

  // --- frag read addressing ---
  const int pr = wv * 4 + q;
  const int lbx = la * 256 + ((pr ^ (la & 7)) * 16);

  f32x4 acc[16];
#pragma unroll
  for (int k = 0; k < 16; k++) acc[k] = (f32x4){0.f, 0.f, 0.f, 0.f};

  const char* sm = (const char*)smem;

#pragma unroll 1
  for (int kt = 0; kt < 4; kt++) {
#pragma unroll
    for (int i = 0; i < 16; i++)
      __builtin_amdgcn_global_load_lds(
          (const __attribute__((address_space(1))) unsigned int*)(AxB + (size_t)i * 65536 + kt * 128),
          (__attribute__((address_space(3))) unsigned int*)(&smem[(i * 256 + wv * 64) * 8]),
          16, 0, 0);
#pragma unroll
    for (int i = 0; i < 16; i++)
      __builtin_amdgcn_global_load_lds(
          (const __attribute__((address_space(1))) unsigned int*)(WxB + (size_t)i * 262144 + kt * 128),
          (__attribute__((address_space(3))) unsigned int*)(&smem[32768 + (i * 256 + wv * 64) * 8]),
          16, 0, 0);
    __syncthreads();

    short8v bv[16];
#pragma unroll
    for (int j = 0; j < 16; j++)
      bv[j] = *(const short8v*)(sm + 65536 + j * 4096 + lbx);

#pragma unroll
    for (int i = 0; i < 16; i++) {
      const short8v a = *(const short8v*)(sm + i * 4096 + lbx);
      const short8v na = neg_bf16x8(a);
#pragma unroll
      for (int j = 0; j < 16; j++) {
        const int k = i ^ j;                 // compile-time after unroll
        acc[k] = __builtin_amdgcn_mfma_f32_16x16x32_bf16(
            (STAB.s[i][j] < 0) ? na : a, bv[j], acc[k], 0, 0, 0);
      }
    }
    __syncthreads();
  }

  // --- epilogue: cross-wave reduction + bias + coalesced float4 out ---
  float* red = (float*)smem;
#pragma unroll
  for (int g = 0; g < 4; g++) {
#pragma unroll
    for (int r2 = 0; r2 < 4; r2++) {
      float4 v = make_float4(acc[g * 4 + 0][r2], acc[g * 4 + 1][r2],
                             acc[g * 4 + 2][r2], acc[g * 4 + 3][r2]);
      int row = q * 4 + r2;                  // C/D: row = quad*4 + reg (m89)
      *(float4*)&red[(((wv * 16 + row) * 16 + la) << 4) + g * 4] = v;
    }
  }
  __syncthreads();

  const int row = tid >> 4, col = tid & 15;
  float4 o[4];
#pragma unroll
  for (int g = 0; g < 4; g++)
    o[g] = *(const float4*)&bias[(u0 + col) * 16 + g * 4];
#pragma unroll
  for (int w2 = 0; w2 < 4; w2++) {
#pragma unroll
    for (int g = 0; g < 4; g++) {
      float4 v = *(const float4*)&red[(((w2 * 16 + row) * 16 + col) << 4) + g * 4];
      o[g].x += v.x; o[g].y += v.y; o[g].z += v.z; o[g].w += v.w;
    }
  }
#pragma unroll
  for (int g = 0; g < 4; g++)
    *(float4*)&out[((size_t)(b0 + row) * 512 + (u0 + col)) * 16 + g * 4] = o[g];
}

// ---------------------------------------------------------------------------
// fallback (ws too small): exact fp32, slow but correct
// ---------------------------------------------------------------------------
__global__ __launch_bounds__(256) void naive_kernel(const float* __restrict__ x,
                                                    const float* __restrict__ w,
                                                    const float* __restrict__ bias,
                                                    float* __restrict__ out) {
  int t = blockIdx.x * 256 + threadIdx.x;
  if (t >= 128 * 512 * 16) return;
  int k = t & 15;
  int u = (t >> 4) & 511;
  int b = t >> 13;
  float sgn[16];
#pragma unroll
  for (int i = 0; i < 16; i++) sgn[i] = (float)ga_sign_i(i, i ^ k);
  float acc = bias[u * 16 + k];
  for (int n = 0; n < 512; n++) {
    const float* xp = x + ((size_t)(b * 512 + n)) * 16;
    const float* wp = w + ((size_t)(u * 512 + n)) * 16;
#pragma unroll
    for (int i = 0; i < 16; i++)
      acc += xp[i] * sgn[i] * wp[i ^ k];
  }
  out[t] = acc;
}

extern "C" void kernel_launch(void* const* d_in, const int* in_sizes, int n_in,
                              void* d_out, int out_size, void* d_ws, size_t ws_size,
                              hipStream_t stream) {
  const float* x    = (const float*)d_in[0];
  const float* w    = (const float*)d_in[1];
  const float* bias = (const float*)d_in[2];
  float* out = (float*)d_out;

  if (ws_size >= WS_NEEDED && d_ws != nullptr) {
    ushort_t* At = (ushort_t*)d_ws;
    ushort_t* Wt = At + AT_ELEMS;

    prep_kernel<<<PREP_BLOCKS, 256, 0, stream>>>(x, w, At, Wt);
    warm_kernel<<<256, 256, 0, stream>>>(At, Wt);
    gemm_kernel<<<256, 256, 0, stream>>>(At, Wt, bias, out);
  } else {
    naive_kernel<<<(128 * 512 * 16) / 256, 256, 0, stream>>>(x, w, bias, out);
  }
}